// Round 4
// baseline (182.908 us; speedup 1.0000x reference)
//
#include <hip/hip_runtime.h>
#include <math.h>

#define NB 16
#define NS 48
#define NL 64
#define NQ 32
#define NE 300
#define NF 256
#define KP 320            // padded K for embeddings (bf16)
#define QROWS 36          // qe rows per b (32 + zero pad for taps)

typedef __attribute__((ext_vector_type(8))) short short8;
typedef __attribute__((ext_vector_type(4))) float f32x4;

#define MFMA(a,b,c) __builtin_amdgcn_mfma_f32_16x16x32_bf16((a),(b),(c),0,0,0)

__device__ __forceinline__ unsigned short f2bf(float f) {
    unsigned u = __float_as_uint(f);
    u += 0x7fff + ((u >> 16) & 1);           // RNE
    return (unsigned short)(u >> 16);
}

// dynamic-LDS byte offsets (s_conv region overlays s_emb region)
#define SE_PITCH 640                        // 320 bf16 per row, 66 rows
#define SC_PITCH 512                        // 256 bf16 per row, 64 rows (overlay)
#define SIM_OFF (66 * 640)                  // 42240
#define SIM_PITCH 66                        // floats per q-row
#define DYN_LDS (SIM_OFF + NQ * SIM_PITCH * 4)   // 50688 bytes

__device__ __forceinline__ float wave_reduce_sum(float v) {
#pragma unroll
    for (int off = 32; off; off >>= 1) v += __shfl_xor(v, off, 64);
    return v;
}
// two independent top-5 pools, interleaved for ILP
__device__ __forceinline__ void top5_pool2(float v1, float v2, int lane,
                                           float& mx1, float& mn1,
                                           float& mx2, float& mn2) {
    float s1 = 0.f, s2 = 0.f, f1 = 0.f, f2 = 0.f;
#pragma unroll
    for (int i = 0; i < 5; ++i) {
        float m1 = v1, m2 = v2;
#pragma unroll
        for (int off = 32; off; off >>= 1) {
            m1 = fmaxf(m1, __shfl_xor(m1, off, 64));
            m2 = fmaxf(m2, __shfl_xor(m2, off, 64));
        }
        if (i == 0) { f1 = m1; f2 = m2; }
        s1 += m1; s2 += m2;
        unsigned long long k1 = __ballot(v1 == m1);
        unsigned long long k2 = __ballot(v2 == m2);
        if (lane == __ffsll(k1) - 1) v1 = -3.4e38f;
        if (lane == __ffsll(k2) - 1) v2 = -3.4e38f;
    }
    mx1 = f1; mn1 = s1 * 0.2f;
    mx2 = f2; mn2 = s2 * 0.2f;
}

// ---------- pack conv_w -> Wb[j][f][k] bf16, k padded to 320; reset done ctr
__global__ void wb_kernel(const float* __restrict__ conv_w, unsigned short* __restrict__ Wb,
                          unsigned int* __restrict__ done_ctr) {
    if (blockIdx.x == 0 && threadIdx.x == 0) done_ctr[0] = 0u;
    int i = blockIdx.x * 256 + threadIdx.x;      // 3*256*320 = 245760
    if (i >= 3 * NF * KP) return;
    int k = i % KP;
    int rest = i / KP;                           // j*256 + f
    int f = rest & 255;
    int j = rest >> 8;
    Wb[i] = (k < NE) ? f2bf(conv_w[(f * 3 + j) * NE + k]) : (unsigned short)0;
}

// ---------- q_emb gather -> bf16 [b][36][320] + q_norm
__global__ void qe_kernel(const int* __restrict__ question, const float* __restrict__ embeds,
                          unsigned short* __restrict__ qe, float* __restrict__ q_norm) {
    int row = blockIdx.x;                        // b*36 + r
    int b = row / QROWS, r = row % QROWS;
    int l = threadIdx.x;
    unsigned short* dst = qe + (size_t)row * KP;
    if (r < NQ) {
        int tok = question[b * NQ + r];
        const float4* rp = (const float4*)(embeds + (size_t)tok * NE);
        float ss;
        {
            float4 v = rp[l];
            ushort4 h = {f2bf(v.x), f2bf(v.y), f2bf(v.z), f2bf(v.w)};
            *(ushort4*)(dst + 4 * l) = h;
            ss = v.x * v.x + v.y * v.y + v.z * v.z + v.w * v.w;
        }
        if (l < 11) {
            float4 v = rp[64 + l];
            ushort4 h = {f2bf(v.x), f2bf(v.y), f2bf(v.z), f2bf(v.w)};
            *(ushort4*)(dst + 256 + 4 * l) = h;
            ss += v.x * v.x + v.y * v.y + v.z * v.z + v.w * v.w;
        }
        if (l < 5) {
            ushort4 z = {0, 0, 0, 0};
            *(ushort4*)(dst + 300 + 4 * l) = z;
        }
        ss = wave_reduce_sum(ss);
        if (l == 0) q_norm[b * NQ + r] = sqrtf(ss);
    } else {
        ushort4 z = {0, 0, 0, 0};
        *(ushort4*)(dst + 4 * l) = z;
        if (l < 16) *(ushort4*)(dst + 256 + 4 * l) = z;
    }
}

// ---------- q_conv via MFMA, spread over 64 blocks: block=(b, fq), wave=f-tile.
__global__ __launch_bounds__(256) void qconv_mfma_kernel(
        const unsigned short* __restrict__ qe, const unsigned short* __restrict__ Wb,
        unsigned short* __restrict__ q_conv) {
    int b = blockIdx.x >> 2, fq = blockIdx.x & 3;
    int tid = threadIdx.x, lane = tid & 63, w = tid >> 6;
    int rl = lane & 15, kg = lane >> 4;
    int f = (fq * 4 + w) * 16 + rl;
    f32x4 acc[2];
    acc[0] = (f32x4){0.f, 0.f, 0.f, 0.f};
    acc[1] = (f32x4){0.f, 0.f, 0.f, 0.f};
    for (int j = 0; j < 3; ++j) {
        for (int ks = 0; ks < 10; ++ks) {
            int k = ks * 32 + kg * 8;
            short8 a0 = *(const short8*)(qe + ((size_t)(b * QROWS) + rl + j) * KP + k);
            short8 a1 = *(const short8*)(qe + ((size_t)(b * QROWS) + 16 + rl + j) * KP + k);
            short8 bb = *(const short8*)(Wb + (size_t)(j * NF + f) * KP + k);
            acc[0] = MFMA(a0, bb, acc[0]);
            acc[1] = MFMA(a1, bb, acc[1]);
        }
    }
#pragma unroll
    for (int m = 0; m < 2; ++m)
#pragma unroll
        for (int reg = 0; reg < 4; ++reg) {
            int q = m * 16 + kg * 4 + reg;
            q_conv[((size_t)(b * NQ) + q) * NF + f] = f2bf(acc[m][reg]);
        }
}

// ---------- qc_norm from bf16 q_conv: one wave per (b,q) row
__global__ void qcn_kernel(const unsigned short* __restrict__ q_conv,
                           float* __restrict__ qc_norm) {
    int row = blockIdx.x;       // 512
    int l = threadIdx.x;
    ushort4 h = *(const ushort4*)(q_conv + (size_t)row * NF + 4 * l);
    float a0 = __uint_as_float((unsigned)h.x << 16);
    float a1 = __uint_as_float((unsigned)h.y << 16);
    float a2 = __uint_as_float((unsigned)h.z << 16);
    float a3 = __uint_as_float((unsigned)h.w << 16);
    float ss = a0 * a0 + a1 * a1 + a2 * a2 + a3 * a3;
    ss = wave_reduce_sum(ss);
    if (l == 0) qc_norm[row] = sqrtf(ss);
}

// ---------- fused per-(b,s), 8 waves: gather -> sim_ins(+norm MFMA) -> pool_ins/conv
//            -> s_conv -> sim_sens(+norm MFMA) -> pools/head
extern __shared__ char ldsc[];
__global__ __launch_bounds__(512, 6) void fused4_kernel(
    const int* __restrict__ sentences, const int* __restrict__ question,
    const float* __restrict__ sim_oh, const float* __restrict__ embeds,
    const unsigned short* __restrict__ Wb,
    const unsigned short* __restrict__ qe, const float* __restrict__ q_norm,
    const unsigned short* __restrict__ q_conv, const float* __restrict__ qc_norm,
    const float* __restrict__ lin_w, const float* __restrict__ lin_b,
    const int* __restrict__ tsent, const int* __restrict__ tdoc,
    unsigned int* __restrict__ done_ctr,
    float* __restrict__ sent_ws, float* __restrict__ d_out)
{
    __shared__ int toks[NL];
    __shared__ float smaskf[NL], snorm[NL], scnorm[NL];
    __shared__ float qn_s[NQ], qcn_s[NQ], qmf_s[NQ];
    __shared__ float wq[8];
    __shared__ float fpool[NQ][2];
    __shared__ int lastflag;
    __shared__ float red2[8];
    __shared__ float dred[NB];

    int tid = threadIdx.x, lane = tid & 63, w = tid >> 6;
    int rl = lane & 15, kg = lane >> 4;
    int mh = w >> 2, tt = w & 3;          // q-half, t-tile
    int bs = blockIdx.x, b = bs / NS;

    // ---- header loads
    if (tid < NL) {
        int tk = sentences[(size_t)bs * NL + tid];
        toks[tid] = tk;
        smaskf[tid] = (tk > 1) ? 1.f : 0.f;
    } else if (tid < NL + NQ) {
        int q = tid - NL;
        qn_s[q] = q_norm[b * NQ + q];
    } else if (tid < NL + 2 * NQ) {
        int q = tid - NL - NQ;
        qcn_s[q] = qc_norm[b * NQ + q];
    } else if (tid < NL + 3 * NQ) {
        int q = tid - NL - 2 * NQ;
        qmf_s[q] = (question[b * NQ + q] > 1) ? 1.f : 0.f;
    }
    __syncthreads();

    // ---- Phase 1: gather s_emb -> LDS bf16 (16B-granule XOR swizzle), stores only
    for (int r = w; r < 66; r += 8) {
        char* rowbase = ldsc + r * SE_PITCH;
        int m7 = r & 7;
        if (r < NL) {
            const float4* rp = (const float4*)(embeds + (size_t)toks[r] * NE);
            {
                float4 v = rp[lane];
                ushort4 h = {f2bf(v.x), f2bf(v.y), f2bf(v.z), f2bf(v.w)};
                *(ushort4*)(rowbase + (((lane >> 1) ^ m7) << 4) + ((lane & 1) << 3)) = h;
            }
            if (lane < 11) {
                float4 v = rp[64 + lane];
                ushort4 h = {f2bf(v.x), f2bf(v.y), f2bf(v.z), f2bf(v.w)};
                int g = 64 + lane;
                *(ushort4*)(rowbase + (((g >> 1) ^ m7) << 4) + ((g & 1) << 3)) = h;
            }
            if (lane < 5) {
                int pk = 37 + ((lane + 1) >> 1);
                int sub = ((lane + 1) & 1) << 3;
                *(unsigned long long*)(rowbase + ((pk ^ m7) << 4) + sub) = 0ull;
            }
        } else {
            if (lane < 40) {
                uint4 z = {0, 0, 0, 0};
                *(uint4*)(rowbase + (lane << 4)) = z;
            }
        }
    }
    __syncthreads();

    // ---- Phase 2: sim_ins MFMA (wave = q-half mh x t-tile tt), waves<4 also s-norm MFMA
    int t = tt * 16 + rl, t7 = t & 7;
    f32x4 iacc = (f32x4){0.f, 0.f, 0.f, 0.f};
    f32x4 nacc = (f32x4){0.f, 0.f, 0.f, 0.f};
    for (int ks = 0; ks < 10; ++ks) {
        int k = ks * 32 + kg * 8;
        short8 bB = *(const short8*)(ldsc + t * SE_PITCH + ((((ks << 2) + kg) ^ t7) << 4));
        short8 a0 = *(const short8*)(qe + (size_t)(b * QROWS + mh * 16 + rl) * KP + k);
        iacc = MFMA(a0, bB, iacc);
        if (w < 4) nacc = MFMA(bB, bB, nacc);
    }
    if (w < 4 && kg == (rl >> 2)) snorm[t] = sqrtf(nacc[rl & 3]);
    __syncthreads();

    // ---- Phase 3: scale + write sim_ins
    {
        float sn_t = snorm[t];
        float inv_sn = smaskf[t] / sn_t;
#pragma unroll
        for (int reg = 0; reg < 4; ++reg) {
            int q = mh * 16 + kg * 4 + reg;
            float sim = iacc[reg] / qn_s[q] * inv_sn * qmf_s[q];
            *(float*)(ldsc + SIM_OFF + (q * SIM_PITCH + t) * 4) = sim;
        }
    }
    __syncthreads();

    // ---- Phase 4: pool sim_ins (wave w owns q = 4w..4w+3), 2-way ILP
    {
        int q0 = w << 2;
        float v0 = *(float*)(ldsc + SIM_OFF + ((q0 + 0) * SIM_PITCH + lane) * 4);
        float v1 = *(float*)(ldsc + SIM_OFF + ((q0 + 1) * SIM_PITCH + lane) * 4);
        float v2 = *(float*)(ldsc + SIM_OFF + ((q0 + 2) * SIM_PITCH + lane) * 4);
        float v3 = *(float*)(ldsc + SIM_OFF + ((q0 + 3) * SIM_PITCH + lane) * 4);
        float a0, a1, b0, b1, c0, c1, d0, d1;
        top5_pool2(v0, v1, lane, a0, a1, b0, b1);
        top5_pool2(v2, v3, lane, c0, c1, d0, d1);
        if (lane == 0) {
            fpool[q0 + 0][0] = a0; fpool[q0 + 0][1] = a1;
            fpool[q0 + 1][0] = b0; fpool[q0 + 1][1] = b1;
            fpool[q0 + 2][0] = c0; fpool[q0 + 2][1] = c1;
            fpool[q0 + 3][0] = d0; fpool[q0 + 3][1] = d1;
        }
    }

    // ---- Phase 5: conv MFMA. wave w owns f-tiles {2w, 2w+1}, all 4 t-tiles.
    f32x4 cacc[4][2];
#pragma unroll
    for (int m = 0; m < 4; ++m)
#pragma unroll
        for (int nn = 0; nn < 2; ++nn) cacc[m][nn] = (f32x4){0.f, 0.f, 0.f, 0.f};
    for (int j = 0; j < 3; ++j) {
        for (int ks = 0; ks < 10; ++ks) {
            int k = ks * 32 + kg * 8;
            short8 a[4], bb[2];
#pragma unroll
            for (int m = 0; m < 4; ++m) {
                int row = m * 16 + rl + j;
                a[m] = *(const short8*)(ldsc + row * SE_PITCH +
                                        ((((ks << 2) + kg) ^ (row & 7)) << 4));
            }
#pragma unroll
            for (int nn = 0; nn < 2; ++nn) {
                int f = ((w << 1) + nn) * 16 + rl;
                bb[nn] = *(const short8*)(Wb + (size_t)(j * NF + f) * KP + k);
            }
#pragma unroll
            for (int m = 0; m < 4; ++m)
#pragma unroll
                for (int nn = 0; nn < 2; ++nn)
                    cacc[m][nn] = MFMA(a[m], bb[nn], cacc[m][nn]);
        }
    }
    __syncthreads();   // all s_emb reads done; s_conv may overwrite

    // ---- Phase 6: write s_conv bf16 into (former s_emb) region
#pragma unroll
    for (int m = 0; m < 4; ++m)
#pragma unroll
        for (int nn = 0; nn < 2; ++nn) {
            int f = ((w << 1) + nn) * 16 + rl;
#pragma unroll
            for (int reg = 0; reg < 4; ++reg) {
                int tr = m * 16 + kg * 4 + reg;
                *(unsigned short*)(ldsc + tr * SC_PITCH +
                                   (((f >> 3) ^ (tr & 7)) << 4) + ((f & 7) << 1)) =
                    f2bf(cacc[m][nn][reg]);
            }
        }
    __syncthreads();

    // ---- Phase 7: prefetch oh; sim_sens MFMA (K=256), waves<4 also sc-norm MFMA
    float oh[4];
#pragma unroll
    for (int qi = 0; qi < 4; ++qi) {
        int q = (w << 2) + qi;
        oh[qi] = sim_oh[((size_t)bs * NQ + q) * NL + lane];
    }
    f32x4 sacc = (f32x4){0.f, 0.f, 0.f, 0.f};
    f32x4 nacc2 = (f32x4){0.f, 0.f, 0.f, 0.f};
    for (int ks = 0; ks < 8; ++ks) {
        int k = ks * 32 + kg * 8;
        short8 bB = *(const short8*)(ldsc + t * SC_PITCH + ((((ks << 2) + kg) ^ t7) << 4));
        short8 a0 = *(const short8*)(q_conv + (size_t)(b * NQ + mh * 16 + rl) * NF + k);
        sacc = MFMA(a0, bB, sacc);
        if (w < 4) nacc2 = MFMA(bB, bB, nacc2);
    }
    if (w < 4 && kg == (rl >> 2)) scnorm[t] = sqrtf(nacc2[rl & 3]);
    __syncthreads();

    // ---- Phase 8: scale + write sim_sens (reuse SIM buffer)
    {
        float inv_scn = 1.f / scnorm[t];
#pragma unroll
        for (int reg = 0; reg < 4; ++reg) {
            int q = mh * 16 + kg * 4 + reg;
            float sim = sacc[reg] / qcn_s[q] * inv_scn;
            *(float*)(ldsc + SIM_OFF + (q * SIM_PITCH + t) * 4) = sim;
        }
    }
    __syncthreads();

    // ---- Phase 9: pool sens + oh + head (wave w owns q = 4w..4w+3)
    {
        float lw0 = lin_w[0], lw1 = lin_w[1], lw2 = lin_w[2];
        float lw3 = lin_w[3], lw4 = lin_w[4], lw5 = lin_w[5];
        float lb = lin_b[0];
        float psum = 0.f;
#pragma unroll
        for (int qi = 0; qi < 4; ++qi) {
            int q = (w << 2) + qi;
            float sv = *(float*)(ldsc + SIM_OFF + (q * SIM_PITCH + lane) * 4);
            float f2, f3, f4, f5;
            top5_pool2(sv, oh[qi], lane, f2, f3, f4, f5);
            float f0 = fpool[q][0], f1 = fpool[q][1];
            float z = f0 * lw0 + f1 * lw1 + f2 * lw2 + f3 * lw3 + f4 * lw4 + f5 * lw5 + lb;
            psum += 1.f / (1.f + expf(-z));
        }
        if (lane == 0) wq[w] = psum;
    }
    __syncthreads();
    if (tid == 0) {
        float sent = (wq[0] + wq[1] + wq[2] + wq[3] + wq[4] + wq[5] + wq[6] + wq[7])
                     * (1.f / 32.f);
        __hip_atomic_store(&sent_ws[bs], sent, __ATOMIC_RELEASE, __HIP_MEMORY_SCOPE_AGENT);
        d_out[1 + bs] = sent;
        unsigned old = atomicAdd(done_ctr, 1u);
        lastflag = (old == (unsigned)(NB * NS - 1)) ? 1 : 0;
    }
    __syncthreads();

    // ---- last block computes losses + doc_emit
    if (lastflag) {
        float acc_l = 0.f;
        for (int i = tid; i < NB * NS; i += 512) {
            float p = __hip_atomic_load(&sent_ws[i], __ATOMIC_ACQUIRE, __HIP_MEMORY_SCOPE_AGENT);
            float tt2 = (float)tsent[i];
            acc_l += tt2 * logf(p) + (1.f - tt2) * logf(1.f - p);
        }
        acc_l = wave_reduce_sum(acc_l);
        if ((tid & 63) == 0) red2[tid >> 6] = acc_l;
        if (tid < NB) {
            float m = -3.4e38f;
            for (int s = 0; s < NS; ++s)
                m = fmaxf(m, __hip_atomic_load(&sent_ws[tid * NS + s], __ATOMIC_ACQUIRE,
                                               __HIP_MEMORY_SCOPE_AGENT));
            d_out[1 + NB * NS + tid] = m;
            float tt2 = (float)tdoc[tid];
            dred[tid] = tt2 * logf(m) + (1.f - tt2) * logf(1.f - m);
        }
        __syncthreads();
        if (tid == 0) {
            float sal = -(red2[0] + red2[1] + red2[2] + red2[3] +
                          red2[4] + red2[5] + red2[6] + red2[7]) / (float)(NB * NS);
            float dsum = 0.f;
            for (int i = 0; i < NB; ++i) dsum += dred[i];
            float dal = -dsum / (float)NB;
            d_out[0] = 0.5f * (sal + dal);
        }
    }
}

extern "C" void kernel_launch(void* const* d_in, const int* in_sizes, int n_in,
                              void* d_out, int out_size, void* d_ws, size_t ws_size,
                              hipStream_t stream) {
    const int* sentences = (const int*)d_in[0];
    const int* question = (const int*)d_in[1];
    const int* tsent = (const int*)d_in[2];
    const int* tdoc = (const int*)d_in[3];
    const float* sim_oh = (const float*)d_in[4];
    const float* embeds = (const float*)d_in[5];
    const float* conv_w = (const float*)d_in[6];
    const float* lin_w = (const float*)d_in[7];
    const float* lin_b = (const float*)d_in[8];
    float* out = (float*)d_out;

    char* wsc = (char*)d_ws;
    unsigned short* Wb     = (unsigned short*)(wsc);             // 491520 B
    unsigned short* qe     = (unsigned short*)(wsc + 491520);    // 368640 B
    float* q_norm          = (float*)(wsc + 860160);             // 2048 B
    unsigned short* q_conv = (unsigned short*)(wsc + 862208);    // 262144 B
    float* qc_norm         = (float*)(wsc + 1124352);            // 2048 B
    float* sent_ws         = (float*)(wsc + 1126400);            // 3072 B
    unsigned int* done_ctr = (unsigned int*)(wsc + 1129472);     // 4 B

    hipFuncSetAttribute(reinterpret_cast<const void*>(fused4_kernel),
                        hipFuncAttributeMaxDynamicSharedMemorySize, DYN_LDS);

    wb_kernel<<<960, 256, 0, stream>>>(conv_w, Wb, done_ctr);
    qe_kernel<<<NB * QROWS, 64, 0, stream>>>(question, embeds, qe, q_norm);
    qconv_mfma_kernel<<<NB * 4, 256, 0, stream>>>(qe, Wb, q_conv);
    qcn_kernel<<<NB * NQ, 64, 0, stream>>>(q_conv, qc_norm);
    fused4_kernel<<<NB * NS, 512, DYN_LDS, stream>>>(
        sentences, question, sim_oh, embeds, Wb, qe, q_norm, q_conv, qc_norm,
        lin_w, lin_b, tsent, tdoc, done_ctr, sent_ws, out);
}

// Round 6
// 130.605 us; speedup vs baseline: 1.4005x; 1.4005x over previous
//
#include <hip/hip_runtime.h>
#include <math.h>

#define NB 16
#define NS 48
#define NL 64
#define NQ 32
#define NE 300
#define NF 256
#define KP 320            // padded K for embeddings (bf16)
#define QROWS 36          // qe rows per b (32 + zero pad for taps)

typedef __attribute__((ext_vector_type(8))) short short8;
typedef __attribute__((ext_vector_type(4))) float f32x4;

#define MFMA(a,b,c) __builtin_amdgcn_mfma_f32_16x16x32_bf16((a),(b),(c),0,0,0)

__device__ __forceinline__ unsigned short f2bf(float f) {
    unsigned u = __float_as_uint(f);
    u += 0x7fff + ((u >> 16) & 1);           // RNE
    return (unsigned short)(u >> 16);
}

// dynamic-LDS byte offsets (s_conv region overlays s_emb region)
#define SE_PITCH 640                        // 320 bf16 per row, 66 rows
#define SC_PITCH 512                        // 256 bf16 per row, 64 rows (overlay)
#define SIM_OFF (66 * 640)                  // 42240
#define SIM_PITCH 66                        // floats per q-row
#define DYN_LDS (SIM_OFF + NQ * SIM_PITCH * 4)   // 50688 bytes

__device__ __forceinline__ float wave_reduce_sum(float v) {
#pragma unroll
    for (int off = 32; off; off >>= 1) v += __shfl_xor(v, off, 64);
    return v;
}

// four independent top-5 pools, interleaved for ILP
__device__ __forceinline__ void top5_pool4(float v0, float v1, float v2, float v3,
                                           int lane, float* mx, float* mn) {
    float s0 = 0.f, s1 = 0.f, s2 = 0.f, s3 = 0.f;
    float x0 = 0.f, x1 = 0.f, x2 = 0.f, x3 = 0.f;
#pragma unroll
    for (int i = 0; i < 5; ++i) {
        float m0 = v0, m1 = v1, m2 = v2, m3 = v3;
#pragma unroll
        for (int off = 32; off; off >>= 1) {
            m0 = fmaxf(m0, __shfl_xor(m0, off, 64));
            m1 = fmaxf(m1, __shfl_xor(m1, off, 64));
            m2 = fmaxf(m2, __shfl_xor(m2, off, 64));
            m3 = fmaxf(m3, __shfl_xor(m3, off, 64));
        }
        if (i == 0) { x0 = m0; x1 = m1; x2 = m2; x3 = m3; }
        s0 += m0; s1 += m1; s2 += m2; s3 += m3;
        unsigned long long k0 = __ballot(v0 == m0);
        unsigned long long k1 = __ballot(v1 == m1);
        unsigned long long k2 = __ballot(v2 == m2);
        unsigned long long k3 = __ballot(v3 == m3);
        if (lane == __ffsll(k0) - 1) v0 = -3.4e38f;
        if (lane == __ffsll(k1) - 1) v1 = -3.4e38f;
        if (lane == __ffsll(k2) - 1) v2 = -3.4e38f;
        if (lane == __ffsll(k3) - 1) v3 = -3.4e38f;
    }
    mx[0] = x0; mx[1] = x1; mx[2] = x2; mx[3] = x3;
    mn[0] = s0 * 0.2f; mn[1] = s1 * 0.2f; mn[2] = s2 * 0.2f; mn[3] = s3 * 0.2f;
}

// ---------- pack conv_w into MFMA B-fragment order:
// Wb2[(c*16 + ftile)*16 + rl] (short8), c=(j*10+ks)*4+kg holds
// conv_w[f=ftile*16+rl][j][k=ks*32+kg*8 .. +7], zero-padded past 300.
__global__ void wb2_kernel(const float* __restrict__ conv_w, short8* __restrict__ Wb2,
                           unsigned int* __restrict__ done_ctr) {
    if (blockIdx.x == 0 && threadIdx.x == 0) done_ctr[0] = 0u;
    int i = blockIdx.x * 256 + threadIdx.x;      // 120*16*16 = 30720
    if (i >= 120 * 256) return;
    int rl = i & 15;
    int ftile = (i >> 4) & 15;
    int c = i >> 8;
    int kg = c & 3, rest = c >> 2;
    int ks = rest % 10, j = rest / 10;
    int f = ftile * 16 + rl;
    int k0 = ks * 32 + kg * 8;
    const float* src = conv_w + (size_t)(f * 3 + j) * NE;
    short8 h;
#pragma unroll
    for (int e = 0; e < 8; ++e) {
        int k = k0 + e;
        h[e] = (short)((k < NE) ? f2bf(src[k]) : (unsigned short)0);
    }
    Wb2[i] = h;
}

// ---------- q_emb gather -> old layout [b][36][320] (conv taps) + A-fragments
// qef[((b*2+mh)*40 + c)*16 + rl] + fp32 q_norm (certified path).
__global__ void qe_kernel(const int* __restrict__ question, const float* __restrict__ embeds,
                          unsigned short* __restrict__ qe, short8* __restrict__ qef,
                          float* __restrict__ q_norm) {
    int row = blockIdx.x;                        // b*36 + r
    int b = row / QROWS, r = row % QROWS;
    int l = threadIdx.x;
    unsigned short* dst = qe + (size_t)row * KP;
    if (r < NQ) {
        int tok = question[b * NQ + r];
        const float4* rp = (const float4*)(embeds + (size_t)tok * NE);
        short8 h = {0, 0, 0, 0, 0, 0, 0, 0};
        float ss = 0.f;
        if (l < 38) {
            float4 v0 = rp[2 * l];
            ss += v0.x * v0.x + v0.y * v0.y + v0.z * v0.z + v0.w * v0.w;
            h[0] = (short)f2bf(v0.x); h[1] = (short)f2bf(v0.y);
            h[2] = (short)f2bf(v0.z); h[3] = (short)f2bf(v0.w);
            if (2 * l + 1 < 75) {
                float4 v1 = rp[2 * l + 1];
                ss += v1.x * v1.x + v1.y * v1.y + v1.z * v1.z + v1.w * v1.w;
                h[4] = (short)f2bf(v1.x); h[5] = (short)f2bf(v1.y);
                h[6] = (short)f2bf(v1.z); h[7] = (short)f2bf(v1.w);
            }
        }
        if (l < 40) {
            *(short8*)(dst + 8 * l) = h;
            qef[((size_t)(b * 2 + (r >> 4)) * 40 + l) * 16 + (r & 15)] = h;
        }
        ss = wave_reduce_sum(ss);
        if (l == 0) q_norm[b * NQ + r] = sqrtf(ss);
    } else {
        if (l < 40) {
            short8 z = {0, 0, 0, 0, 0, 0, 0, 0};
            *(short8*)(dst + 8 * l) = z;
        }
    }
}

// ---------- q_conv via MFMA -> A-fragments qcf[((b*2+mh)*32 + c)*16 + rl].
// grid = (b, fq): 64 blocks of 256. Wave w does ftile = fq*4+w.
__global__ __launch_bounds__(256) void qconv_mfma_kernel(
        const unsigned short* __restrict__ qe, const short8* __restrict__ Wb2,
        short8* __restrict__ qcf) {
    __shared__ unsigned short tile[NQ][72];      // f-local 64, pitch 72
    int b = blockIdx.x >> 2, fq = blockIdx.x & 3;
    int tid = threadIdx.x, lane = tid & 63, w = tid >> 6;
    int rl = lane & 15, kg = lane >> 4;
    int ftile = fq * 4 + w;
    f32x4 acc0 = (f32x4){0.f, 0.f, 0.f, 0.f};
    f32x4 acc1 = (f32x4){0.f, 0.f, 0.f, 0.f};
    for (int j = 0; j < 3; ++j) {
#pragma unroll 2
        for (int ks = 0; ks < 10; ++ks) {
            int k = ks * 32 + kg * 8;
            int c = (j * 10 + ks) * 4 + kg;
            short8 a0 = *(const short8*)(qe + ((size_t)(b * QROWS) + rl + j) * KP + k);
            short8 a1 = *(const short8*)(qe + ((size_t)(b * QROWS) + 16 + rl + j) * KP + k);
            short8 bb = Wb2[(c * 16 + ftile) * 16 + rl];
            acc0 = MFMA(a0, bb, acc0);
            acc1 = MFMA(a1, bb, acc1);
        }
    }
    int fl = w * 16 + rl;
#pragma unroll
    for (int reg = 0; reg < 4; ++reg) {
        tile[kg * 4 + reg][fl] = f2bf(acc0[reg]);
        tile[16 + kg * 4 + reg][fl] = f2bf(acc1[reg]);
    }
    __syncthreads();
    // emit fragments: thread -> (mh, c_local, rl2)
    int mh = tid >> 7, c_local = (tid >> 4) & 7, rl2 = tid & 15;
    short8 h = *(const short8*)(&tile[mh * 16 + rl2][c_local * 8]);
    qcf[((size_t)(b * 2 + mh) * 32 + 8 * fq + c_local) * 16 + rl2] = h;
}

// ---------- qc_norm from bf16 qcf fragments (fp32 sum — certified r4 semantics)
__global__ __launch_bounds__(256) void qcn_kernel(const short8* __restrict__ qcf,
                                                  float* __restrict__ qc_norm) {
    __shared__ float part[2][16][8];
    int b = blockIdx.x;
    int tid = threadIdx.x;
    int mh = tid >> 7, sub = (tid >> 4) & 7, rl = tid & 15;
    const short8* base = qcf + ((size_t)(b * 2 + mh) * 32) * 16;
    float ss = 0.f;
#pragma unroll
    for (int i = 0; i < 4; ++i) {
        short8 h = base[(sub * 4 + i) * 16 + rl];
#pragma unroll
        for (int e = 0; e < 8; ++e) {
            float v = __uint_as_float(((unsigned)(unsigned short)h[e]) << 16);
            ss += v * v;
        }
    }
    part[mh][rl][sub] = ss;
    __syncthreads();
    if (tid < 32) {
        int m2 = tid >> 4, r2 = tid & 15;
        float s = 0.f;
#pragma unroll
        for (int k = 0; k < 8; ++k) s += part[m2][r2][k];
        qc_norm[b * NQ + m2 * 16 + r2] = sqrtf(s);
    }
}

// ---------- fused per-(b,s), 4 waves.
extern __shared__ char ldsc[];
__global__ __launch_bounds__(256, 3) void fused6_kernel(
    const int* __restrict__ sentences, const int* __restrict__ question,
    const float* __restrict__ sim_oh, const float* __restrict__ embeds,
    const short8* __restrict__ Wb2,
    const short8* __restrict__ qef, const short8* __restrict__ qcf,
    const float* __restrict__ q_norm, const float* __restrict__ qc_norm,
    const float* __restrict__ lin_w, const float* __restrict__ lin_b,
    const int* __restrict__ tsent, const int* __restrict__ tdoc,
    unsigned int* __restrict__ done_ctr,
    float* __restrict__ sent_ws, float* __restrict__ d_out)
{
    __shared__ int toks[NL];
    __shared__ float smaskf[NL], snorm[NL], scnorm[NL];
    __shared__ float qn_s[NQ], qcn_s[NQ], qmf_s[NQ];
    __shared__ float wq[4];
    __shared__ float fpool[NQ][2];
    __shared__ int lastflag;
    __shared__ float red2[4];
    __shared__ float dred[NB];

    int tid = threadIdx.x, lane = tid & 63, w = tid >> 6;
    int rl = lane & 15, kg = lane >> 4;
    int bs = blockIdx.x, b = bs / NS;
    int t = (w << 4) + rl, t7 = t & 7;

    // ---- header loads (fp32 norms from certified producers)
    if (tid < NL) {
        int tk = sentences[(size_t)bs * NL + tid];
        toks[tid] = tk;
        smaskf[tid] = (tk > 1) ? 1.f : 0.f;
    } else if (tid < NL + NQ) {
        int q = tid - NL;
        qn_s[q] = q_norm[b * NQ + q];
    } else if (tid < NL + 2 * NQ) {
        int q = tid - NL - NQ;
        qcn_s[q] = qc_norm[b * NQ + q];
    } else if (tid < NL + 3 * NQ) {
        int q = tid - NL - 2 * NQ;
        qmf_s[q] = (question[b * NQ + q] > 1) ? 1.f : 0.f;
    }
    __syncthreads();

    // ---- Phase 1: gather s_emb -> LDS bf16 (16B-granule XOR swizzle), stores only
#pragma unroll 2
    for (int r = w; r < 66; r += 4) {
        char* rowbase = ldsc + r * SE_PITCH;
        int m7 = r & 7;
        if (r < NL) {
            const float4* rp = (const float4*)(embeds + (size_t)toks[r] * NE);
            {
                float4 v = rp[lane];
                ushort4 h = {f2bf(v.x), f2bf(v.y), f2bf(v.z), f2bf(v.w)};
                *(ushort4*)(rowbase + (((lane >> 1) ^ m7) << 4) + ((lane & 1) << 3)) = h;
            }
            if (lane < 11) {
                float4 v = rp[64 + lane];
                ushort4 h = {f2bf(v.x), f2bf(v.y), f2bf(v.z), f2bf(v.w)};
                int g = 64 + lane;
                *(ushort4*)(rowbase + (((g >> 1) ^ m7) << 4) + ((g & 1) << 3)) = h;
            }
            if (lane < 5) {
                int pk = 37 + ((lane + 1) >> 1);
                int sub = ((lane + 1) & 1) << 3;
                *(unsigned long long*)(rowbase + ((pk ^ m7) << 4) + sub) = 0ull;
            }
        } else {
            if (lane < 40) {
                uint4 z = {0, 0, 0, 0};
                *(uint4*)(rowbase + (lane << 4)) = z;
            }
        }
    }
    __syncthreads();

    // ---- Phase 2: sim_ins MFMA (wave w = t-tile, M=32 q) + snorm via Gram diag
    {
        f32x4 iacc0 = (f32x4){0.f, 0.f, 0.f, 0.f};
        f32x4 iacc1 = (f32x4){0.f, 0.f, 0.f, 0.f};
        f32x4 nB = (f32x4){0.f, 0.f, 0.f, 0.f};
        const short8* qf = qef + (size_t)(b * 80) * 16;
#pragma unroll 2
        for (int ks = 0; ks < 10; ++ks) {
            int c = ks * 4 + kg;
            short8 bB = *(const short8*)(ldsc + t * SE_PITCH + ((c ^ t7) << 4));
            short8 a0 = qf[c * 16 + rl];
            short8 a1 = qf[(40 + c) * 16 + rl];
            iacc0 = MFMA(a0, bB, iacc0);
            iacc1 = MFMA(a1, bB, iacc1);
            nB = MFMA(bB, bB, nB);
        }
        if (kg == (rl >> 2)) snorm[t] = sqrtf(nB[rl & 3]);
        __syncthreads();

        // ---- Phase 3: scale + write sim_ins
        float inv_t = smaskf[t] / snorm[t];
#pragma unroll
        for (int reg = 0; reg < 4; ++reg) {
            int q0 = kg * 4 + reg;
            float s0 = iacc0[reg] / qn_s[q0] * inv_t * qmf_s[q0];
            *(float*)(ldsc + SIM_OFF + (q0 * SIM_PITCH + t) * 4) = s0;
            int q1 = 16 + kg * 4 + reg;
            float s1 = iacc1[reg] / qn_s[q1] * inv_t * qmf_s[q1];
            *(float*)(ldsc + SIM_OFF + (q1 * SIM_PITCH + t) * 4) = s1;
        }
    }
    __syncthreads();

    // ---- Phase 4: pool sim_ins (wave w owns q = 8w..8w+7), 4-way ILP
    {
        int q0 = w << 3;
        float v[8];
#pragma unroll
        for (int qi = 0; qi < 8; ++qi)
            v[qi] = *(float*)(ldsc + SIM_OFF + ((q0 + qi) * SIM_PITCH + lane) * 4);
        float mx[4], mn[4];
        top5_pool4(v[0], v[1], v[2], v[3], lane, mx, mn);
        if (lane == 0)
#pragma unroll
            for (int p = 0; p < 4; ++p) { fpool[q0 + p][0] = mx[p]; fpool[q0 + p][1] = mn[p]; }
        top5_pool4(v[4], v[5], v[6], v[7], lane, mx, mn);
        if (lane == 0)
#pragma unroll
            for (int p = 0; p < 4; ++p) { fpool[q0 + 4 + p][0] = mx[p]; fpool[q0 + 4 + p][1] = mn[p]; }
    }

    // ---- Phase 5: conv MFMA. wave w owns f-tiles 4w..4w+3, all 4 t-tiles.
    f32x4 cacc[4][4];
#pragma unroll
    for (int m = 0; m < 4; ++m)
#pragma unroll
        for (int nn = 0; nn < 4; ++nn) cacc[m][nn] = (f32x4){0.f, 0.f, 0.f, 0.f};
    for (int j = 0; j < 3; ++j) {
#pragma unroll 2
        for (int ks = 0; ks < 10; ++ks) {
            int c = (j * 10 + ks) * 4 + kg;
            short8 a[4], bb[4];
#pragma unroll
            for (int m = 0; m < 4; ++m) {
                int row = m * 16 + rl + j;
                a[m] = *(const short8*)(ldsc + row * SE_PITCH +
                                        ((((ks << 2) + kg) ^ (row & 7)) << 4));
            }
#pragma unroll
            for (int nn = 0; nn < 4; ++nn)
                bb[nn] = Wb2[(c * 16 + (w * 4 + nn)) * 16 + rl];
#pragma unroll
            for (int m = 0; m < 4; ++m)
#pragma unroll
                for (int nn = 0; nn < 4; ++nn)
                    cacc[m][nn] = MFMA(a[m], bb[nn], cacc[m][nn]);
        }
    }
    __syncthreads();   // all s_emb reads done; s_conv may overwrite

    // ---- Phase 6: write s_conv bf16 into (former s_emb) region
#pragma unroll
    for (int m = 0; m < 4; ++m)
#pragma unroll
        for (int nn = 0; nn < 4; ++nn) {
            int f = (w * 4 + nn) * 16 + rl;
#pragma unroll
            for (int reg = 0; reg < 4; ++reg) {
                int tr = m * 16 + kg * 4 + reg;
                *(unsigned short*)(ldsc + tr * SC_PITCH +
                                   (((f >> 3) ^ (tr & 7)) << 4) + ((f & 7) << 1)) =
                    f2bf(cacc[m][nn][reg]);
            }
        }
    __syncthreads();

    // ---- Phase 7: prefetch oh; sim_sens MFMA (K=256) + scnorm via Gram diag
    float oh[8];
#pragma unroll
    for (int qi = 0; qi < 8; ++qi) {
        int q = (w << 3) + qi;
        oh[qi] = sim_oh[((size_t)bs * NQ + q) * NL + lane];
    }
    {
        f32x4 sacc0 = (f32x4){0.f, 0.f, 0.f, 0.f};
        f32x4 sacc1 = (f32x4){0.f, 0.f, 0.f, 0.f};
        f32x4 nB = (f32x4){0.f, 0.f, 0.f, 0.f};
        const short8* qc = qcf + (size_t)(b * 64) * 16;
#pragma unroll 2
        for (int ks = 0; ks < 8; ++ks) {
            int c = ks * 4 + kg;
            short8 bB = *(const short8*)(ldsc + t * SC_PITCH + ((c ^ t7) << 4));
            short8 a0 = qc[c * 16 + rl];
            short8 a1 = qc[(32 + c) * 16 + rl];
            sacc0 = MFMA(a0, bB, sacc0);
            sacc1 = MFMA(a1, bB, sacc1);
            nB = MFMA(bB, bB, nB);
        }
        if (kg == (rl >> 2)) scnorm[t] = sqrtf(nB[rl & 3]);
        __syncthreads();

        // ---- Phase 8: scale + write sim_sens (reuse SIM buffer)
        float inv_t = 1.f / scnorm[t];
#pragma unroll
        for (int reg = 0; reg < 4; ++reg) {
            int q0 = kg * 4 + reg;
            *(float*)(ldsc + SIM_OFF + (q0 * SIM_PITCH + t) * 4) =
                sacc0[reg] / qcn_s[q0] * inv_t;
            int q1 = 16 + kg * 4 + reg;
            *(float*)(ldsc + SIM_OFF + (q1 * SIM_PITCH + t) * 4) =
                sacc1[reg] / qcn_s[q1] * inv_t;
        }
    }
    __syncthreads();

    // ---- Phase 9: pool sens + oh + head (wave w owns q = 8w..8w+7)
    {
        float lw0 = lin_w[0], lw1 = lin_w[1], lw2 = lin_w[2];
        float lw3 = lin_w[3], lw4 = lin_w[4], lw5 = lin_w[5];
        float lb = lin_b[0];
        int q0 = w << 3;
        float sv[8];
#pragma unroll
        for (int qi = 0; qi < 8; ++qi)
            sv[qi] = *(float*)(ldsc + SIM_OFF + ((q0 + qi) * SIM_PITCH + lane) * 4);
        float mxs[8], mns[8], mxo[8], mno[8];
        top5_pool4(sv[0], sv[1], sv[2], sv[3], lane, mxs, mns);
        top5_pool4(sv[4], sv[5], sv[6], sv[7], lane, mxs + 4, mns + 4);
        top5_pool4(oh[0], oh[1], oh[2], oh[3], lane, mxo, mno);
        top5_pool4(oh[4], oh[5], oh[6], oh[7], lane, mxo + 4, mno + 4);
        float psum = 0.f;
#pragma unroll
        for (int qi = 0; qi < 8; ++qi) {
            float f0 = fpool[q0 + qi][0], f1 = fpool[q0 + qi][1];
            float z = f0 * lw0 + f1 * lw1 + mxs[qi] * lw2 + mns[qi] * lw3 +
                      mxo[qi] * lw4 + mno[qi] * lw5 + lb;
            psum += 1.f / (1.f + expf(-z));
        }
        if (lane == 0) wq[w] = psum;
    }
    __syncthreads();
    if (tid == 0) {
        float sent = (wq[0] + wq[1] + wq[2] + wq[3]) * (1.f / 32.f);
        __hip_atomic_store(&sent_ws[bs], sent, __ATOMIC_RELEASE, __HIP_MEMORY_SCOPE_AGENT);
        d_out[1 + bs] = sent;
        unsigned old = atomicAdd(done_ctr, 1u);
        lastflag = (old == (unsigned)(NB * NS - 1)) ? 1 : 0;
    }
    __syncthreads();

    // ---- last block computes losses + doc_emit
    if (lastflag) {
        float acc_l = 0.f;
        for (int i = tid; i < NB * NS; i += 256) {
            float p = __hip_atomic_load(&sent_ws[i], __ATOMIC_ACQUIRE, __HIP_MEMORY_SCOPE_AGENT);
            float tt2 = (float)tsent[i];
            acc_l += tt2 * logf(p) + (1.f - tt2) * logf(1.f - p);
        }
        acc_l = wave_reduce_sum(acc_l);
        if ((tid & 63) == 0) red2[tid >> 6] = acc_l;
        if (tid < NB) {
            float m = -3.4e38f;
            for (int s = 0; s < NS; ++s)
                m = fmaxf(m, __hip_atomic_load(&sent_ws[tid * NS + s], __ATOMIC_ACQUIRE,
                                               __HIP_MEMORY_SCOPE_AGENT));
            d_out[1 + NB * NS + tid] = m;
            float tt2 = (float)tdoc[tid];
            dred[tid] = tt2 * logf(m) + (1.f - tt2) * logf(1.f - m);
        }
        __syncthreads();
        if (tid == 0) {
            float sal = -(red2[0] + red2[1] + red2[2] + red2[3]) / (float)(NB * NS);
            float dsum = 0.f;
            for (int i = 0; i < NB; ++i) dsum += dred[i];
            float dal = -dsum / (float)NB;
            d_out[0] = 0.5f * (sal + dal);
        }
    }
}

extern "C" void kernel_launch(void* const* d_in, const int* in_sizes, int n_in,
                              void* d_out, int out_size, void* d_ws, size_t ws_size,
                              hipStream_t stream) {
    const int* sentences = (const int*)d_in[0];
    const int* question = (const int*)d_in[1];
    const int* tsent = (const int*)d_in[2];
    const int* tdoc = (const int*)d_in[3];
    const float* sim_oh = (const float*)d_in[4];
    const float* embeds = (const float*)d_in[5];
    const float* conv_w = (const float*)d_in[6];
    const float* lin_w = (const float*)d_in[7];
    const float* lin_b = (const float*)d_in[8];
    float* out = (float*)d_out;

    char* wsc = (char*)d_ws;
    short8* Wb2            = (short8*)(wsc);                     // 491520 B
    unsigned short* qe_old = (unsigned short*)(wsc + 491520);    // 368640 B
    short8* qef            = (short8*)(wsc + 860160);            // 327680 B
    short8* qcf            = (short8*)(wsc + 1187840);           // 262144 B
    float* q_norm          = (float*)(wsc + 1449984);            // 2048 B
    float* qc_norm         = (float*)(wsc + 1452032);            // 2048 B
    float* sent_ws         = (float*)(wsc + 1454080);            // 3072 B
    unsigned int* done_ctr = (unsigned int*)(wsc + 1457152);     // 4 B

    hipFuncSetAttribute(reinterpret_cast<const void*>(fused6_kernel),
                        hipFuncAttributeMaxDynamicSharedMemorySize, DYN_LDS);

    wb2_kernel<<<120, 256, 0, stream>>>(conv_w, Wb2, done_ctr);
    qe_kernel<<<NB * QROWS, 64, 0, stream>>>(question, embeds, qe_old, qef, q_norm);
    qconv_mfma_kernel<<<NB * 4, 256, 0, stream>>>(qe_old, Wb2, qcf);
    qcn_kernel<<<NB, 256, 0, stream>>>(qcf, qc_norm);
    fused6_kernel<<<NB * NS, 256, DYN_LDS, stream>>>(
        sentences, question, sim_oh, embeds, Wb2, qef, qcf, q_norm, qc_norm,
        lin_w, lin_b, tsent, tdoc, done_ctr, sent_ws, out);
}